// Round 1
// baseline (516.390 us; speedup 1.0000x reference)
//
#include <hip/hip_runtime.h>
#include <math.h>

#define IN_DIM 128
#define OUT_DIM 64
#define NEG_SLOPE 0.2f

// ---------------------------------------------------------------- init
__global__ void init_kernel(float* __restrict__ emax, float* __restrict__ denom, int n) {
    int i = blockIdx.x * blockDim.x + threadIdx.x;
    if (i < n) {
        emax[i]  = -INFINITY;
        denom[i] = 0.f;
    }
}

// ---------------------------------------------------------------- h = X@W, el = h@a_l, er = h@a_r
// One wave per row: lane = output column (OUT_DIM==64==wavefront).
__global__ __launch_bounds__(256) void gemm_kernel(
        const float* __restrict__ X, const float* __restrict__ W,
        const float* __restrict__ a_l, const float* __restrict__ a_r,
        float* __restrict__ h, float* __restrict__ el, float* __restrict__ er, int n)
{
    __shared__ float Wl[IN_DIM * OUT_DIM];   // 32 KB
    __shared__ float Xl[4][IN_DIM];          // 2 KB
    const int tid  = threadIdx.x;
    const int wave = tid >> 6;
    const int lane = tid & 63;

    for (int i = tid; i < IN_DIM * OUT_DIM; i += 256) Wl[i] = W[i];
    __syncthreads();

    const int row = blockIdx.x * 4 + wave;
    if (row >= n) return;

    // stage this wave's X row into LDS (float2 per lane, coalesced)
    const float2 xr = ((const float2*)(X + (size_t)row * IN_DIM))[lane];
    Xl[wave][lane * 2]     = xr.x;
    Xl[wave][lane * 2 + 1] = xr.y;
    // same-wave LDS write->read: ordered by lgkmcnt, no barrier needed

    float acc = 0.f;
    #pragma unroll
    for (int k = 0; k < IN_DIM; k += 4) {
        acc += Xl[wave][k]     * Wl[(k    ) * OUT_DIM + lane];
        acc += Xl[wave][k + 1] * Wl[(k + 1) * OUT_DIM + lane];
        acc += Xl[wave][k + 2] * Wl[(k + 2) * OUT_DIM + lane];
        acc += Xl[wave][k + 3] * Wl[(k + 3) * OUT_DIM + lane];
    }
    h[(size_t)row * OUT_DIM + lane] = acc;

    // wave-reduce el/er
    float vl = acc * a_l[lane];
    float vr = acc * a_r[lane];
    #pragma unroll
    for (int off = 32; off > 0; off >>= 1) {
        vl += __shfl_xor(vl, off);
        vr += __shfl_xor(vr, off);
    }
    if (lane == 0) { el[row] = vl; er[row] = vr; }
}

// ---------------------------------------------------------------- float atomic max
__device__ inline void atomicMaxFloat(float* addr, float val) {
    if (val >= 0.f) atomicMax((int*)addr, __float_as_int(val));
    else            atomicMin((unsigned int*)addr, __float_as_uint(val));
}

// ---------------------------------------------------------------- edge logits + segment max
__global__ void edge_max_kernel(
        const int* __restrict__ src, const int* __restrict__ dst,
        const float* __restrict__ el, const float* __restrict__ er,
        float* __restrict__ e, float* __restrict__ emax, int ecount)
{
    int i = blockIdx.x * blockDim.x + threadIdx.x;
    if (i >= ecount) return;
    int s = src[i], d = dst[i];
    float x = el[s] + er[d];
    x = (x > 0.f) ? x : NEG_SLOPE * x;
    e[i] = x;
    atomicMaxFloat(&emax[d], x);
}

// ---------------------------------------------------------------- exp + segment sum (w overwrites e)
__global__ void edge_exp_kernel(
        const int* __restrict__ dst, float* __restrict__ e,
        const float* __restrict__ emax, float* __restrict__ denom, int ecount)
{
    int i = blockIdx.x * blockDim.x + threadIdx.x;
    if (i >= ecount) return;
    int d = dst[i];
    float x = expf(e[i] - emax[d]);
    e[i] = x;
    atomicAdd(&denom[d], x);
}

// ---------------------------------------------------------------- weighted scatter-add
// One wave per edge, lane = channel.
__global__ __launch_bounds__(256) void aggregate_kernel(
        const int* __restrict__ src, const int* __restrict__ dst,
        const float* __restrict__ w, const float* __restrict__ denom,
        const float* __restrict__ h, float* __restrict__ out, int ecount)
{
    const int edge = blockIdx.x * 4 + (threadIdx.x >> 6);
    const int lane = threadIdx.x & 63;
    if (edge >= ecount) return;
    const int s = src[edge], d = dst[edge];
    const float alpha = w[edge] / fmaxf(denom[d], 1e-16f);
    const float val = alpha * h[(size_t)s * OUT_DIM + lane];
    atomicAdd(&out[(size_t)d * OUT_DIM + lane], val);
}

// ---------------------------------------------------------------- launch
extern "C" void kernel_launch(void* const* d_in, const int* in_sizes, int n_in,
                              void* d_out, int out_size, void* d_ws, size_t ws_size,
                              hipStream_t stream) {
    const float* X   = (const float*)d_in[0];
    const int*   ei  = (const int*)  d_in[1];
    const float* W   = (const float*)d_in[2];
    const float* a_l = (const float*)d_in[3];
    const float* a_r = (const float*)d_in[4];
    float* out = (float*)d_out;

    const int n = in_sizes[0] / IN_DIM;   // 100000
    const int e = in_sizes[1] / 2;        // 1000000
    const int* src = ei;
    const int* dst = ei + e;

    // workspace carve-up (256B aligned)
    char* ws = (char*)d_ws;
    auto carve = [&](size_t bytes) {
        char* p = ws;
        ws += (bytes + 255) & ~(size_t)255;
        return p;
    };
    float* h     = (float*)carve((size_t)n * OUT_DIM * sizeof(float)); // 25.6 MB
    float* el    = (float*)carve((size_t)n * sizeof(float));
    float* er    = (float*)carve((size_t)n * sizeof(float));
    float* emax  = (float*)carve((size_t)n * sizeof(float));
    float* denom = (float*)carve((size_t)n * sizeof(float));
    float* ew    = (float*)carve((size_t)e * sizeof(float));           // logits, then exp-weights

    hipMemsetAsync(d_out, 0, (size_t)out_size * sizeof(float), stream);
    init_kernel<<<(n + 255) / 256, 256, 0, stream>>>(emax, denom, n);
    gemm_kernel<<<(n + 3) / 4, 256, 0, stream>>>(X, W, a_l, a_r, h, el, er, n);
    edge_max_kernel<<<(e + 255) / 256, 256, 0, stream>>>(src, dst, el, er, ew, emax, e);
    edge_exp_kernel<<<(e + 255) / 256, 256, 0, stream>>>(dst, ew, emax, denom, e);
    aggregate_kernel<<<(e + 3) / 4, 256, 0, stream>>>(src, dst, ew, denom, h, out, e);
}